// Round 8
// baseline (287.087 us; speedup 1.0000x reference)
//
#include <hip/hip_runtime.h>
#include <hip/hip_bf16.h>

// FlowNetC correlation via bf16 MFMA, fp32 accumulate.
// out[b, r*21+dx, y, x] = (1/256) * sum_c in1[b,c,y,x] * in2[b,c, y+2r-20, x+2dx-20]
//
// Round-12: ABLATION ROUND (sacrificial timing). Seven structural variants
// (r5 60.5 / r6 66.4 / r8 67.2 / r9 63.6 / r10 84.8 / r11 63.0) all pinned
// at 60-67us with every pipe <=28% busy -- hypothesis-driven optimization is
// exhausted. This round decomposes the 63us empirically: three diagnostic
// kernels (DCE-proofed with asm-volatile sinks) run BEFORE the real pair:
//   abl_load : per-iter B-loads only               -> load-path marginal cost
//   abl_mfma : A-setup + B-loads + MFMA            -> +A-setup +MFMA cost
//   abl_epi  : A-setup + reg-fed MFMA + epilogue   -> epilogue/store cost
//              (writes garbage to out; corr_full rewrites EVERY out element
//               afterwards on the same stream, so the final result is correct)
//   corr_full: unchanged r11 kernel (writes the real output last)
// rocprof per-dispatch dur+counters give the decomposition; next round
// attacks whichever phase owns the time.

typedef short    bf16x8 __attribute__((ext_vector_type(8)));
typedef float    f32x4  __attribute__((ext_vector_type(4)));

constexpr int CSTRIDE = 64 * 64;        // fp32 channel plane
constexpr int BSTRIDE = 256 * CSTRIDE;  // fp32 batch

union BF2 { __hip_bfloat162 h; unsigned u; };

__device__ inline unsigned pack_bf2(float lo, float hi) {
    BF2 cv;
    cv.h = __float22bfloat162_rn(make_float2(lo, hi));
    return cv.u;
}

#define ELT(v4, xi) ((xi) == 0 ? (v4).x : (xi) == 1 ? (v4).y : (xi) == 2 ? (v4).z : (v4).w)

__device__ __align__(16) const uint4 ZERO16 = {0u, 0u, 0u, 0u};

// ---------------- prepass: in2 -> bf16 frag-native chunks ----------------
__global__ __launch_bounds__(256)
void conv_in2(const float* __restrict__ in2, uint4* __restrict__ out16)
{
    const int tid = threadIdx.x;
    const int b  = blockIdx.x & 7;             // XCD affinity
    const int y  = (blockIdx.x >> 3) & 63;
    const int hf = blockIdx.x >> 9;            // c8 half
    const int c8 = (tid >> 4) + 16 * hf;       // 0..31
    const int x0 = (tid & 15) * 4;             // 4 consecutive x per thread
    const float* p = in2 + b * BSTRIDE + y * 64 + c8 * 8 * CSTRIDE + x0;
    uint4* dst = out16 + (b * 64 + y) * 2048 + c8 * 64 + x0;

    float4 v[8];
#pragma unroll
    for (int j = 0; j < 8; ++j)
        v[j] = *reinterpret_cast<const float4*>(p + j * CSTRIDE);
#pragma unroll
    for (int xi = 0; xi < 4; ++xi) {
        uint4 o;
        o.x = pack_bf2(ELT(v[0], xi), ELT(v[1], xi));
        o.y = pack_bf2(ELT(v[2], xi), ELT(v[3], xi));
        o.z = pack_bf2(ELT(v[4], xi), ELT(v[5], xi));
        o.w = pack_bf2(ELT(v[6], xi), ELT(v[7], xi));
        dst[xi] = o;
    }
}

// ---------------- shared A-fragment builder ----------------
__device__ inline void build_af(const float* __restrict__ in1, int b, int y0,
                                int m, int cl, int q, bf16x8 af[2][8])
{
#pragma unroll
    for (int h = 0; h < 2; ++h) {
        const float* pb = in1 + b * BSTRIDE + (y0 + 2 * h) * 64 + 16 * m + cl
                        + 8 * q * CSTRIDE;
#pragma unroll
        for (int k = 0; k < 8; ++k) {
            const float* pp = pb + 32 * k * CSTRIDE;
            float v[8];
#pragma unroll
            for (int j = 0; j < 8; ++j) v[j] = pp[j * CSTRIDE];
#pragma unroll
            for (int j = 0; j < 4; ++j)
                ((unsigned*)&af[h][k])[j] = pack_bf2(v[2 * j], v[2 * j + 1]);
        }
    }
}

// ================= DIAGNOSTIC 1: B-load path only =================
__global__ __launch_bounds__(256, 4)
void abl_load(const uint4* __restrict__ in2t)
{
    const int tid  = threadIdx.x;
    const int lane = tid & 63;
    const int cl   = lane & 15;
    const int q    = lane >> 4;
    const int m    = tid >> 6;
    const int b    = blockIdx.x & 7;
    const int p    = (blockIdx.x >> 3) & 31;
    const int d    = blockIdx.x >> 8;
    const int n    = m + d;
    const int y0   = 4 * (p >> 1) + (p & 1);
    const int x    = 16 * n + cl - 20;
    const bool xok = (x >= 0) && (x < 64);

    for (int i = 0; i < 22; ++i) {
        const int yy = y0 - 20 + 2 * i;
        if (yy >= 0 && yy < 64) {
            const uint4* src = in2t + (b * 64 + yy) * 2048 + x;
            uint4 wv[8];
#pragma unroll
            for (int k = 0; k < 8; ++k) {
                const uint4* pk = xok ? (src + (4 * k + q) * 64) : &ZERO16;
                wv[k] = *pk;
            }
#pragma unroll
            for (int k = 0; k < 8; ++k)
                asm volatile("" :: "v"(wv[k].x), "v"(wv[k].y),
                                   "v"(wv[k].z), "v"(wv[k].w));
        }
    }
}

// ================= DIAGNOSTIC 2: A-setup + B-loads + MFMA =================
__global__ __launch_bounds__(256, 4)
void abl_mfma(const float* __restrict__ in1, const uint4* __restrict__ in2t)
{
    const int tid  = threadIdx.x;
    const int lane = tid & 63;
    const int cl   = lane & 15;
    const int q    = lane >> 4;
    const int m    = tid >> 6;
    const int b    = blockIdx.x & 7;
    const int p    = (blockIdx.x >> 3) & 31;
    const int d    = blockIdx.x >> 8;
    const int n    = m + d;
    const int y0   = 4 * (p >> 1) + (p & 1);

    bf16x8 af[2][8];
    build_af(in1, b, y0, m, cl, q, af);

    const int  x   = 16 * n + cl - 20;
    const bool xok = (x >= 0) && (x < 64);

    for (int i = 0; i < 22; ++i) {
        const int  yy      = y0 - 20 + 2 * i;
        const bool compute = (yy >= 0) && (yy < 64);
        const bool h0v     = (i <= 20);
        const bool h1v     = (i >= 1);
        if (compute) {
            f32x4 acc0 = {0.f, 0.f, 0.f, 0.f};
            f32x4 acc1 = {0.f, 0.f, 0.f, 0.f};
            const uint4* src = in2t + (b * 64 + yy) * 2048 + x;
#pragma unroll
            for (int kb = 0; kb < 2; ++kb) {
                uint4 wv[4];
#pragma unroll
                for (int k4 = 0; k4 < 4; ++k4) {
                    const int k = kb * 4 + k4;
                    const uint4* pk = xok ? (src + (4 * k + q) * 64) : &ZERO16;
                    wv[k4] = *pk;
                }
#pragma unroll
                for (int k4 = 0; k4 < 4; ++k4) {
                    const int k = kb * 4 + k4;
                    const bf16x8 bf = __builtin_bit_cast(bf16x8, wv[k4]);
                    if (h0v) acc0 = __builtin_amdgcn_mfma_f32_16x16x32_bf16(af[0][k], bf, acc0, 0, 0, 0);
                    if (h1v) acc1 = __builtin_amdgcn_mfma_f32_16x16x32_bf16(af[1][k], bf, acc1, 0, 0, 0);
                }
            }
            asm volatile("" :: "v"(acc0[0]), "v"(acc0[1]), "v"(acc0[2]), "v"(acc0[3]),
                               "v"(acc1[0]), "v"(acc1[1]), "v"(acc1[2]), "v"(acc1[3]));
        }
    }
}

// ================= DIAGNOSTIC 3: A-setup + reg-fed MFMA + epilogue =================
// Writes garbage into out; corr_full rewrites every element afterwards.
__global__ __launch_bounds__(256, 4)
void abl_epi(const float* __restrict__ in1, float* __restrict__ out)
{
    __shared__ float slds[4][2][21][17];

    const int tid  = threadIdx.x;
    const int lane = tid & 63;
    const int w    = tid >> 6;
    const int cl   = lane & 15;
    const int q    = lane >> 4;
    const int m    = w;
    const int b    = blockIdx.x & 7;
    const int p    = (blockIdx.x >> 3) & 31;
    const int d    = blockIdx.x >> 8;
    const int y0   = 4 * (p >> 1) + (p & 1);

    bf16x8 af[2][8];
    build_af(in1, b, y0, m, cl, q, af);

    const int lo_e = (d == 0) ? 0 : 16 * d - 14;
    const int hi_e = (16 * d + 14 > 40) ? 40 : 16 * d + 14;
    const int cnt    = ((hi_e - lo_e) >> 1) + 1;
    const int rounds = (cnt + 3) >> 2;

    float* ms = &slds[w][0][0][0];
    const int s   = lane >> 4;
    const int pos = lane & 15;

    for (int i = 0; i < 22; ++i) {
        const int  yy      = y0 - 20 + 2 * i;
        const bool compute = (yy >= 0) && (yy < 64);
        const bool h0v     = (i <= 20);
        const bool h1v     = (i >= 1);

        if (compute) {
            f32x4 acc0 = {(float)i * 1e-8f, 0.f, 0.f, 0.f};   // defeat LICM
            f32x4 acc1 = {(float)i * 1e-8f, 0.f, 0.f, 0.f};
#pragma unroll
            for (int k = 0; k < 8; ++k) {        // B comes from registers (af)
                if (h0v) acc0 = __builtin_amdgcn_mfma_f32_16x16x32_bf16(af[0][k], af[1][k], acc0, 0, 0, 0);
                if (h1v) acc1 = __builtin_amdgcn_mfma_f32_16x16x32_bf16(af[1][k], af[0][k], acc1, 0, 0, 0);
            }
#pragma unroll
            for (int i4 = 0; i4 < 4; ++i4) {
                const int gxl = 4 * q + i4;
                const int d2  = 16 * d + cl - gxl;
                if (d2 >= 0 && d2 <= 40 && !(d2 & 1)) {
                    const int off = (d2 >> 1) * 17 + gxl;
                    if (h0v) ms[off]       = acc0[i4];
                    if (h1v) ms[357 + off] = acc1[i4];
                }
            }
        }
        for (int rd = 0; rd < rounds; ++rd) {
            const int d2 = lo_e + 2 * (rd * 4 + s);
            const int al = (16 * d > d2) ? (16 * d - d2) : 0;
            int bl = 16 * d + 16 - d2; if (bl > 16) bl = 16;
            const bool act = (d2 <= hi_e) && (pos >= al) && (pos < bl);
            if (act) {
                const int off = (d2 >> 1) * 17 + pos;
                const int gx  = 16 * m + pos;
                if (h0v) {
                    const float v = compute ? ms[off] * (1.f / 256.f) : 0.f;
                    out[((b * 441 + i * 21 + (d2 >> 1)) * 64 + y0) * 64 + gx] = v;
                }
                if (h1v) {
                    const float v = compute ? ms[357 + off] * (1.f / 256.f) : 0.f;
                    out[((b * 441 + (i - 1) * 21 + (d2 >> 1)) * 64 + (y0 + 2)) * 64 + gx] = v;
                }
            }
        }
    }
}

// ================= REAL kernel (unchanged r11; runs LAST) =================
__global__ __launch_bounds__(256, 4)
void corr_mfma(const float* __restrict__ in1,
               const uint4* __restrict__ in2t,
               float* __restrict__ out)
{
    __shared__ float slds[4][2][21][17];

    const int tid  = threadIdx.x;
    const int lane = tid & 63;
    const int w    = tid >> 6;
    const int cl   = lane & 15;
    const int q    = lane >> 4;
    const int m    = w;
    const int b    = blockIdx.x & 7;
    const int p    = (blockIdx.x >> 3) & 31;
    const int d    = blockIdx.x >> 8;
    const int n    = m + d;
    const int y0   = 4 * (p >> 1) + (p & 1);

    bf16x8 af[2][8];
    build_af(in1, b, y0, m, cl, q, af);

    const int  x   = 16 * n + cl - 20;
    const bool xok = (x >= 0) && (x < 64);

    const int lo_e = (d == 0) ? 0 : 16 * d - 14;
    const int hi_e = (16 * d + 14 > 40) ? 40 : 16 * d + 14;
    const int cnt    = ((hi_e - lo_e) >> 1) + 1;
    const int rounds = (cnt + 3) >> 2;

    float* ms = &slds[w][0][0][0];
    const int s   = lane >> 4;
    const int pos = lane & 15;

    for (int i = 0; i < 22; ++i) {
        const int  yy      = y0 - 20 + 2 * i;
        const bool compute = (yy >= 0) && (yy < 64);
        const bool h0v     = (i <= 20);
        const bool h1v     = (i >= 1);

        if (compute) {
            f32x4 acc0 = {0.f, 0.f, 0.f, 0.f};
            f32x4 acc1 = {0.f, 0.f, 0.f, 0.f};
            const uint4* src = in2t + (b * 64 + yy) * 2048 + x;
#pragma unroll
            for (int kb = 0; kb < 2; ++kb) {
                uint4 wv[4];
#pragma unroll
                for (int k4 = 0; k4 < 4; ++k4) {
                    const int k = kb * 4 + k4;
                    const uint4* pk = xok ? (src + (4 * k + q) * 64) : &ZERO16;
                    wv[k4] = *pk;
                }
#pragma unroll
                for (int k4 = 0; k4 < 4; ++k4) {
                    const int k = kb * 4 + k4;
                    const bf16x8 bf = __builtin_bit_cast(bf16x8, wv[k4]);
                    if (h0v) acc0 = __builtin_amdgcn_mfma_f32_16x16x32_bf16(af[0][k], bf, acc0, 0, 0, 0);
                    if (h1v) acc1 = __builtin_amdgcn_mfma_f32_16x16x32_bf16(af[1][k], bf, acc1, 0, 0, 0);
                }
            }
#pragma unroll
            for (int i4 = 0; i4 < 4; ++i4) {
                const int gxl = 4 * q + i4;
                const int d2  = 16 * d + cl - gxl;
                if (d2 >= 0 && d2 <= 40 && !(d2 & 1)) {
                    const int off = (d2 >> 1) * 17 + gxl;
                    if (h0v) ms[off]       = acc0[i4];
                    if (h1v) ms[357 + off] = acc1[i4];
                }
            }
        }

        for (int rd = 0; rd < rounds; ++rd) {
            const int d2 = lo_e + 2 * (rd * 4 + s);
            const int al = (16 * d > d2) ? (16 * d - d2) : 0;
            int bl = 16 * d + 16 - d2; if (bl > 16) bl = 16;
            const bool act = (d2 <= hi_e) && (pos >= al) && (pos < bl);
            if (act) {
                const int off = (d2 >> 1) * 17 + pos;
                const int gx  = 16 * m + pos;
                if (h0v) {
                    const float v = compute ? ms[off] * (1.f / 256.f) : 0.f;
                    out[((b * 441 + i * 21 + (d2 >> 1)) * 64 + y0) * 64 + gx] = v;
                }
                if (h1v) {
                    const float v = compute ? ms[357 + off] * (1.f / 256.f) : 0.f;
                    out[((b * 441 + (i - 1) * 21 + (d2 >> 1)) * 64 + (y0 + 2)) * 64 + gx] = v;
                }
            }
        }
    }
}

extern "C" void kernel_launch(void* const* d_in, const int* in_sizes, int n_in,
                              void* d_out, int out_size, void* d_ws, size_t ws_size,
                              hipStream_t stream) {
    const float* in1 = (const float*)d_in[0];
    const float* in2 = (const float*)d_in[1];
    float* out = (float*)d_out;

    conv_in2<<<dim3(1024), dim3(256), 0, stream>>>(in2, (uint4*)d_ws);
    // --- diagnostics (timing decomposition; out garbage is overwritten below) ---
    abl_load<<<dim3(1024), dim3(256), 0, stream>>>((const uint4*)d_ws);
    abl_mfma<<<dim3(1024), dim3(256), 0, stream>>>(in1, (const uint4*)d_ws);
    abl_epi <<<dim3(1024), dim3(256), 0, stream>>>(in1, out);
    // --- real kernel (writes every out element) ---
    corr_mfma<<<dim3(1024), dim3(256), 0, stream>>>(in1, (const uint4*)d_ws, out);
}